// Round 1
// baseline (95.139 us; speedup 1.0000x reference)
//
#include <hip/hip_runtime.h>
#include <math.h>

namespace {
constexpr int BS    = 4;
constexpr int LSZ   = 256;
constexpr int CROPD = 246;
constexpr int NPTS  = BS * LSZ * LSZ;      // 262144
constexpr int NCROP = BS * CROPD * CROPD;  // 242064

constexpr int SZ_OMSI   = BS * 4 * CROPD * CROPD;
constexpr int SZ_OOFF   = BS * CROPD * CROPD * 2;
constexpr int SZ_PREMSI = BS * CROPD * CROPD;
constexpr int SZ_PREPAN = BS * CROPD * CROPD;
constexpr int SZ_OFFSET = NPTS * 2;
constexpr int SZ_SPEKC  = BS * CROPD * CROPD * 5;

constexpr int OFF_OMSI   = 0;
constexpr int OFF_OOFF   = OFF_OMSI + SZ_OMSI;
constexpr int OFF_PREMSI = OFF_OOFF + SZ_OOFF;
constexpr int OFF_PREPAN = OFF_PREMSI + SZ_PREMSI;
constexpr int OFF_OFFSET = OFF_PREPAN + SZ_PREPAN;
constexpr int OFF_SPEKC  = OFF_OFFSET + SZ_OFFSET;
constexpr int OFF_SPAK   = OFF_SPEKC + SZ_SPEKC;
} // namespace

// ---------------- Kernel A: per-point MLP + heads ----------------
// f1 = relu(coords @ w1 + b1)   (200)
// f2 = relu(f1 @ w2 + b2)       (50)
// offset = f2@wo+bo (2), spek = f2@wse+bse (5), spak0 = f2@wsa+bsa (4)
__global__ __launch_bounds__(256) void mlp_kernel(
    const float* __restrict__ coords,
    const float* __restrict__ w1, const float* __restrict__ b1,
    const float* __restrict__ w2, const float* __restrict__ b2,
    const float* __restrict__ wo, const float* __restrict__ bo,
    const float* __restrict__ wse, const float* __restrict__ bse,
    const float* __restrict__ wsa, const float* __restrict__ bsa,
    float* __restrict__ out)
{
    const int n = blockIdx.x * blockDim.x + threadIdx.x;
    if (n >= NPTS) return;

    const float c0 = coords[2 * n + 0];
    const float c1 = coords[2 * n + 1];

    float f2[50];
#pragma unroll
    for (int j = 0; j < 50; ++j) f2[j] = 0.0f;

    for (int k = 0; k < 200; ++k) {
        float h = fmaf(c0, w1[k], fmaf(c1, w1[200 + k], b1[k]));
        h = fmaxf(h, 0.0f);
        const float* w2row = w2 + k * 50;
#pragma unroll
        for (int j = 0; j < 50; ++j) f2[j] = fmaf(h, w2row[j], f2[j]);
    }
#pragma unroll
    for (int j = 0; j < 50; ++j) f2[j] = fmaxf(f2[j] + b2[j], 0.0f);

    float off0 = bo[0], off1 = bo[1];
    float se[5];
#pragma unroll
    for (int s = 0; s < 5; ++s) se[s] = bse[s];
    float sa[4];
#pragma unroll
    for (int i = 0; i < 4; ++i) sa[i] = bsa[i];

#pragma unroll
    for (int j = 0; j < 50; ++j) {
        const float f = f2[j];
        off0 = fmaf(f, wo[2 * j + 0], off0);
        off1 = fmaf(f, wo[2 * j + 1], off1);
#pragma unroll
        for (int s = 0; s < 5; ++s) se[s] = fmaf(f, wse[5 * j + s], se[s]);
#pragma unroll
        for (int i = 0; i < 4; ++i) sa[i] = fmaf(f, wsa[4 * j + i], sa[i]);
    }

    // full offset output
    out[OFF_OFFSET + 2 * n + 0] = off0;
    out[OFF_OFFSET + 2 * n + 1] = off1;
    // full spak0 output
#pragma unroll
    for (int i = 0; i < 4; ++i) out[OFF_SPAK + 4 * n + i] = sa[i];

    // cropped spek_c output
    const int b = n >> 16;
    const int hw = n & 0xFFFF;
    const int h = hw >> 8;
    const int w = hw & 0xFF;
    if (h >= 5 && h < 251 && w >= 5 && w < 251) {
        const int base = OFF_SPEKC + (((b * CROPD) + (h - 5)) * CROPD + (w - 5)) * 5;
#pragma unroll
        for (int s = 0; s < 5; ++s) out[base + s] = se[s];
    }
}

// ---------------- Kernel B: spatially-variant Gaussian conv on pan ----------
__global__ __launch_bounds__(256) void prepan_kernel(
    const float* __restrict__ pan,
    float* __restrict__ out)
{
    const int t = blockIdx.x * blockDim.x + threadIdx.x;
    if (t >= NCROP) return;

    const int b  = t / (CROPD * CROPD);
    const int r  = t % (CROPD * CROPD);
    const int hh = r / CROPD;
    const int ww = r % CROPD;
    const int h = hh + 5, w = ww + 5;
    const int n = (b << 16) + (h << 8) + w;

    const float* spak = out + OFF_SPAK;
    const float a = spak[4 * n + 0];
    const float c = spak[4 * n + 2];
    const float d = spak[4 * n + 3];
    // m = [[a,0],[c,d]], inv = m^T m
    const float inv00 = a * a + c * c;
    const float inv01 = c * d;
    const float inv11 = d * d;

    // For cropped h,w in [5,250]: rows/cols = 4h+p-6 in [14,1008], always valid.
    const float* prow = pan + ((size_t)b << 20) + (size_t)(4 * h - 6) * 1024 + (4 * w - 6);

    float ksum = 0.0f, conv = 0.0f;
#pragma unroll
    for (int p = 0; p < 15; ++p) {
        const float gp  = (float)(p - 7);
        const float tp  = inv00 * gp * gp;
        const float tpq = 2.0f * inv01 * gp;
        const float* pr = prow + p * 1024;
#pragma unroll
        for (int q = 0; q < 15; ++q) {
            const float gq = (float)(q - 7);
            const float tt = fmaf(inv11 * gq, gq, fmaf(tpq, gq, tp));
            const float kv = __expf(-0.5f * tt);
            ksum += kv;
            conv = fmaf(kv, pr[q], conv);
        }
    }
    out[OFF_PREPAN + t] = conv / ksum;
}

// ---------------- Kernel C: grid-sample + o_offset + pre_msi ----------------
__global__ __launch_bounds__(256) void sample_kernel(
    const float* __restrict__ msi,
    float* __restrict__ out)
{
    const int t = blockIdx.x * blockDim.x + threadIdx.x;
    if (t >= NCROP) return;

    const int b  = t / (CROPD * CROPD);
    const int r  = t % (CROPD * CROPD);
    const int hh = r / CROPD;
    const int ww = r % CROPD;
    const int h = hh + 5, w = ww + 5;
    const int n = (b << 16) + (h << 8) + w;

    const float off0 = out[OFF_OFFSET + 2 * n + 0];
    const float off1 = out[OFF_OFFSET + 2 * n + 1];
    // o_offset
    out[OFF_OOFF + 2 * t + 0] = off0;
    out[OFF_OOFF + 2 * t + 1] = off1;

    // grid = base + offset/LS*2 ; lin = linspace(-1,1,256)
    const float gx = fmaf((float)w, 2.0f / 255.0f, -1.0f) + off0 * (1.0f / 128.0f);
    const float gy = fmaf((float)h, 2.0f / 255.0f, -1.0f) + off1 * (1.0f / 128.0f);

    const float px = (gx + 1.0f) * 0.5f * 255.0f;
    const float py = (gy + 1.0f) * 0.5f * 255.0f;
    const float x0f = floorf(px), y0f = floorf(py);
    const float wx1 = px - x0f,  wy1 = py - y0f;
    const int x0 = (int)x0f, y0 = (int)y0f;
    const int x1 = x0 + 1,  y1 = y0 + 1;

    const bool vx0 = (x0 >= 0) & (x0 < 256);
    const bool vx1 = (x1 >= 0) & (x1 < 256);
    const bool vy0 = (y0 >= 0) & (y0 < 256);
    const bool vy1 = (y1 >= 0) & (y1 < 256);
    const int cx0 = min(max(x0, 0), 255), cx1 = min(max(x1, 0), 255);
    const int cy0 = min(max(y0, 0), 255), cy1 = min(max(y1, 0), 255);

    const float w00 = (1.0f - wy1) * (1.0f - wx1) * (float)(vy0 & vx0);
    const float w01 = (1.0f - wy1) * wx1          * (float)(vy0 & vx1);
    const float w10 = wy1 * (1.0f - wx1)          * (float)(vy1 & vx0);
    const float w11 = wy1 * wx1                   * (float)(vy1 & vx1);

    const int i00 = cy0 * 256 + cx0;
    const int i01 = cy0 * 256 + cx1;
    const int i10 = cy1 * 256 + cx0;
    const int i11 = cy1 * 256 + cx1;

    const float* mb = msi + ((size_t)b * 4) * 65536;
    const float* spc = out + OFF_SPEKC + 5 * t;   // written by mlp_kernel

    float pm = spc[4];   // "ones" channel
#pragma unroll
    for (int ch = 0; ch < 4; ++ch) {
        const float* mc = mb + ch * 65536;
        float v = w00 * mc[i00] + w01 * mc[i01] + w10 * mc[i10] + w11 * mc[i11];
        out[OFF_OMSI + (((b * 4) + ch) * CROPD + hh) * CROPD + ww] = v;
        pm = fmaf(v, spc[ch], pm);
    }
    out[OFF_PREMSI + t] = pm;
}

extern "C" void kernel_launch(void* const* d_in, const int* in_sizes, int n_in,
                              void* d_out, int out_size, void* d_ws, size_t ws_size,
                              hipStream_t stream)
{
    const float* msi    = (const float*)d_in[0];
    const float* pan    = (const float*)d_in[1];
    const float* coords = (const float*)d_in[2];
    const float* w1  = (const float*)d_in[3];
    const float* b1  = (const float*)d_in[4];
    const float* w2  = (const float*)d_in[5];
    const float* b2  = (const float*)d_in[6];
    const float* wo  = (const float*)d_in[7];
    const float* bo  = (const float*)d_in[8];
    const float* wse = (const float*)d_in[9];
    const float* bse = (const float*)d_in[10];
    const float* wsa = (const float*)d_in[11];
    const float* bsa = (const float*)d_in[12];
    float* out = (float*)d_out;

    mlp_kernel<<<NPTS / 256, 256, 0, stream>>>(coords, w1, b1, w2, b2,
                                               wo, bo, wse, bse, wsa, bsa, out);
    const int gcrop = (NCROP + 255) / 256;
    prepan_kernel<<<gcrop, 256, 0, stream>>>(pan, out);
    sample_kernel<<<gcrop, 256, 0, stream>>>(msi, out);
}